// Round 1
// baseline (3430.961 us; speedup 1.0000x reference)
//
#include <hip/hip_runtime.h>
#include <math.h>

#define G      64      // workgroups in persistent kernel
#define NT     256     // threads per workgroup
#define H      256
#define CTX    128
#define V      33
#define T      220
#define BATCH  1024
#define HBSTR  768     // 3*H, one h-buffer (all layers)

// ---- workspace layout (float offsets) ----
#define WS_EMB 64                      // [V][1024] precomputed layer0 x-part + biases
#define WS_HB  (WS_EMB + V*1024)       // [2][3][H] double-buffered h
#define WS_PL  (WS_HB + 2*3*H)         // [G][V] partial logits
#define WS_PR  (WS_PL + G*V)           // [T][V] compact predictions
// total = 64 + 33792 + 1536 + 2112 + 7260 = 44764 floats (~175 KB)

__device__ __forceinline__ float gld(const float* p) {
  return __hip_atomic_load(p, __ATOMIC_RELAXED, __HIP_MEMORY_SCOPE_AGENT);
}
__device__ __forceinline__ void gst(float* p, float v) {
  __hip_atomic_store(p, v, __ATOMIC_RELAXED, __HIP_MEMORY_SCOPE_AGENT);
}
__device__ __forceinline__ float sigf(float x) { return 1.f / (1.f + expf(-x)); }

__device__ __forceinline__ float red16(float a) {
  #pragma unroll
  for (int m = 8; m; m >>= 1) a += __shfl_xor(a, m, 16);
  return a;
}

// dot of one weight row (256 cols) with a 256-float LDS vector; 16 lanes/row.
__device__ __forceinline__ float dot16(const float* __restrict__ Wrow,
                                       const float* __restrict__ xsh, int lane) {
  const float4* w4 = reinterpret_cast<const float4*>(Wrow) + lane * 4;
  const float4* x4 = reinterpret_cast<const float4*>(xsh) + lane * 4;
  float a = 0.f;
  #pragma unroll
  for (int m = 0; m < 4; ++m) {
    float4 w = w4[m], x = x4[m];
    a += w.x * x.x + w.y * x.y + w.z * x.z + w.w * x.w;
  }
  return a;
}

// grid barrier: monotonic counter, release-RMW arrival, acquire-spin.
__device__ __forceinline__ void gbar(unsigned* ctr, unsigned target) {
  __syncthreads();   // all waves' agent-stores complete (vmcnt drain) before arrival
  if (threadIdx.x == 0) {
    __hip_atomic_fetch_add(ctr, 1u, __ATOMIC_RELEASE, __HIP_MEMORY_SCOPE_AGENT);
    while (__hip_atomic_load(ctr, __ATOMIC_ACQUIRE, __HIP_MEMORY_SCOPE_AGENT) < target)
      __builtin_amdgcn_s_sleep(1);
  }
  __syncthreads();
}

__global__ __launch_bounds__(NT) void speller_persistent(
    const float* __restrict__ embed,     // [V][H]
    const float* __restrict__ Wih0,      // [4H][H+CTX]
    const float* __restrict__ Wih_rest,  // [2][4H][H]
    const float* __restrict__ Whh,       // [3][4H][H]
    const float* __restrict__ bih,       // [3][4H]
    const float* __restrict__ bhh,       // [3][4H]
    const float* __restrict__ W1,        // [H][H+CTX]
    const float* __restrict__ b1,        // [H]
    const float* __restrict__ W2,        // [V][H]
    const float* __restrict__ b2,        // [V]
    const float* __restrict__ h0,        // [3][H]
    const float* __restrict__ c0,        // [3][H]
    float* __restrict__ ws)
{
  __shared__ __align__(16) float sh_emb[V * H];   // precompute only
  __shared__ __align__(16) float sh_x[H];
  __shared__ __align__(16) float sh_h[H];
  __shared__ float sh_g[16];
  __shared__ float sh_f[4];
  __shared__ float sh_logits[V];
  __shared__ int   sh_char;

  const int tid  = threadIdx.x, wg = blockIdx.x;
  const int r    = tid >> 4, lane = tid & 15;   // 16 rows x 16 lanes
  const int gate = r >> 2,  jj   = r & 3;
  const int wrow = gate * H + wg * 4 + jj;      // gate-row index in [0,1024)

  unsigned* ctr = reinterpret_cast<unsigned*>(ws);
  float* EMB = ws + WS_EMB;
  float* HB  = ws + WS_HB;
  float* PL  = ws + WS_PL;
  float* PR  = ws + WS_PR;

  // --- per-WG-owned c state (threads 0..3 hold one h-index each, all layers) ---
  float c0r = 0.f, c1r = 0.f, c2r = 0.f;
  if (tid < 4) {
    c0r = c0[0 * H + wg * 4 + tid];
    c1r = c0[1 * H + wg * 4 + tid];
    c2r = c0[2 * H + wg * 4 + tid];
  }
  // --- h init into buffer 1 (= (t=0 - 1) & 1) ---
  if (wg < 3) gst(HB + HBSTR + wg * H + tid, h0[wg * H + tid]);

  // --- precompute EMB[v][row] = embed[v] . Wih0[row,:256] + bih0[row] + bhh0[row] ---
  for (int i = tid; i < V * H; i += NT) sh_emb[i] = embed[i];
  __syncthreads();
  {
    const int prow = wg * 16 + r;   // each WG owns 16 of the 1024 rows
    const float4* w4 = reinterpret_cast<const float4*>(
        Wih0 + (size_t)prow * (H + CTX) + lane * 16);
    const float4 w0 = w4[0], w1 = w4[1], w2 = w4[2], w3 = w4[3];
    const float bs = bih[prow] + bhh[prow];
    for (int v = 0; v < V; ++v) {
      const float4* e4 = reinterpret_cast<const float4*>(sh_emb + v * H + lane * 16);
      float4 e0 = e4[0], e1 = e4[1], e2 = e4[2], e3 = e4[3];
      float a = w0.x*e0.x + w0.y*e0.y + w0.z*e0.z + w0.w*e0.w
              + w1.x*e1.x + w1.y*e1.y + w1.z*e1.z + w1.w*e1.w
              + w2.x*e2.x + w2.y*e2.y + w2.z*e2.z + w2.w*e2.w
              + w3.x*e3.x + w3.y*e3.y + w3.z*e3.z + w3.w*e3.w;
      a = red16(a);
      if (lane == 0) gst(EMB + v * 1024 + prow, a + bs);
    }
  }
  unsigned nbar = 1;
  gbar(ctr, nbar * G);

  int chr = 0;
  for (int t = 0; t < T; ++t) {
    const int cur = t & 1, prv = cur ^ 1;

    // ================= Stage A: finish logits(t-1) + layer 0 =================
    float pls[G];
    const bool lg = (t > 0) && (tid < V);
    if (lg) {
      #pragma unroll
      for (int g = 0; g < G; ++g) pls[g] = gld(PL + g * V + tid);
    }
    sh_h[tid] = gld(HB + prv * HBSTR + 0 * H + tid);   // h0_{t-1}
    __syncthreads();
    float acc = dot16(Whh + (size_t)wrow * H, sh_h, lane);   // layer0 h-dot (char-free)
    if (t > 0) {
      if (lg) {
        float s = b2[tid];
        #pragma unroll
        for (int g = 0; g < G; ++g) s += pls[g];
        sh_logits[tid] = s;
        if (wg == 0) PR[(t - 1) * V + tid] = s;   // plain store: read by next kernel
      }
      __syncthreads();
      if (tid == 0) {
        float best = sh_logits[0]; int bv = 0;
        for (int v = 1; v < V; ++v)
          if (sh_logits[v] > best) { best = sh_logits[v]; bv = v; }
        sh_char = bv;                              // first-max tie-break == argmax
      }
      __syncthreads();
      chr = sh_char;
    }
    acc = red16(acc);
    if (lane == 0) sh_g[r] = acc + EMB[chr * 1024 + wrow];
    __syncthreads();
    if (tid < 4) {
      float gi = sh_g[tid], gf = sh_g[4 + tid], gg = sh_g[8 + tid], go = sh_g[12 + tid];
      float cn = sigf(gf) * c0r + sigf(gi) * tanhf(gg);
      c0r = cn;
      gst(HB + cur * HBSTR + 0 * H + wg * 4 + tid, sigf(go) * tanhf(cn));
    }
    nbar++; gbar(ctr, nbar * G);

    // ================= Stage B: layer 1 =================
    sh_x[tid] = gld(HB + cur * HBSTR + 0 * H + tid);   // h0_t
    sh_h[tid] = gld(HB + prv * HBSTR + 1 * H + tid);   // h1_{t-1}
    __syncthreads();
    acc = dot16(Wih_rest + (size_t)wrow * H, sh_x, lane)
        + dot16(Whh + (size_t)1 * 1024 * H + (size_t)wrow * H, sh_h, lane);
    acc = red16(acc);
    if (lane == 0) sh_g[r] = acc + bih[1024 + wrow] + bhh[1024 + wrow];
    __syncthreads();
    if (tid < 4) {
      float gi = sh_g[tid], gf = sh_g[4 + tid], gg = sh_g[8 + tid], go = sh_g[12 + tid];
      float cn = sigf(gf) * c1r + sigf(gi) * tanhf(gg);
      c1r = cn;
      gst(HB + cur * HBSTR + 1 * H + wg * 4 + tid, sigf(go) * tanhf(cn));
    }
    nbar++; gbar(ctr, nbar * G);

    // ================= Stage C: layer 2 =================
    sh_x[tid] = gld(HB + cur * HBSTR + 1 * H + tid);   // h1_t
    sh_h[tid] = gld(HB + prv * HBSTR + 2 * H + tid);   // h2_{t-1}
    __syncthreads();
    acc = dot16(Wih_rest + (size_t)1024 * H + (size_t)wrow * H, sh_x, lane)
        + dot16(Whh + (size_t)2 * 1024 * H + (size_t)wrow * H, sh_h, lane);
    acc = red16(acc);
    if (lane == 0) sh_g[r] = acc + bih[2048 + wrow] + bhh[2048 + wrow];
    __syncthreads();
    if (tid < 4) {
      float gi = sh_g[tid], gf = sh_g[4 + tid], gg = sh_g[8 + tid], go = sh_g[12 + tid];
      float cn = sigf(gf) * c2r + sigf(gi) * tanhf(gg);
      c2r = cn;
      gst(HB + cur * HBSTR + 2 * H + wg * 4 + tid, sigf(go) * tanhf(cn));
    }
    nbar++; gbar(ctr, nbar * G);

    // ================= Stage D: classifier (f rows + partial logits) =================
    sh_x[tid] = gld(HB + cur * HBSTR + 2 * H + tid);   // h2_t
    __syncthreads();
    if (tid < 64) {
      const int fr = tid >> 4;            // 0..3
      const int jf = wg * 4 + fr;
      float a = dot16(W1 + (size_t)jf * (H + CTX), sh_x, lane);
      a = red16(a);
      if (lane == 0) sh_f[fr] = fmaxf(a + b1[jf], 0.f);
    }
    __syncthreads();
    if (tid < V) {
      float s = 0.f;
      #pragma unroll
      for (int q = 0; q < 4; ++q)
        s += W2[(size_t)tid * H + wg * 4 + q] * sh_f[q];
      gst(PL + wg * V + tid, s);
    }
    nbar++; gbar(ctr, nbar * G);
  }

  // final logits for t = T-1
  if (wg == 0 && tid < V) {
    float s = b2[tid];
    #pragma unroll
    for (int g = 0; g < G; ++g) s += gld(PL + g * V + tid);
    PR[(T - 1) * V + tid] = s;   // flushed at kernel end
  }
}

// broadcast compact [T][V] predictions to [B][T][V]
__global__ __launch_bounds__(NT) void bcast_kernel(const float* __restrict__ PR,
                                                   float* __restrict__ out) {
  float* o = out + (size_t)blockIdx.x * (T * V);
  for (int i = threadIdx.x; i < T * V; i += NT) o[i] = PR[i];
}

extern "C" void kernel_launch(void* const* d_in, const int* in_sizes, int n_in,
                              void* d_out, int out_size, void* d_ws, size_t ws_size,
                              hipStream_t stream) {
  const float* embed    = (const float*)d_in[1];
  const float* Wih0     = (const float*)d_in[2];
  const float* Wih_rest = (const float*)d_in[3];
  const float* Whh      = (const float*)d_in[4];
  const float* bih      = (const float*)d_in[5];
  const float* bhh      = (const float*)d_in[6];
  const float* W1       = (const float*)d_in[7];
  const float* b1       = (const float*)d_in[8];
  const float* W2       = (const float*)d_in[9];
  const float* b2       = (const float*)d_in[10];
  const float* h0       = (const float*)d_in[11];
  const float* c0       = (const float*)d_in[12];
  float* out = (float*)d_out;
  float* ws  = (float*)d_ws;

  // zero the barrier counter (ws is poisoned 0xAA before every launch)
  hipMemsetAsync(d_ws, 0, 256, stream);

  speller_persistent<<<G, NT, 0, stream>>>(embed, Wih0, Wih_rest, Whh, bih, bhh,
                                           W1, b1, W2, b2, h0, c0, ws);
  bcast_kernel<<<BATCH, NT, 0, stream>>>(ws + WS_PR, out);
}